// Round 11
// baseline (43.895 us; speedup 1.0000x reference)
//
#include <hip/hip_runtime.h>
#include <math.h>

// Problem constants
#define BATCH   8
#define LDIM    20
#define PIX     25600   // 160*160
#define NLPAIRS 400     // N*L
#define NLR     800     // N*L*2

// Projection decomposition: lane owns 4 pixels, wave owns 8 rows.
#define PPB     256                 // pixels per block (64 lanes * 4)
#define NPX     (PIX / PPB)         // 100 pixel-slices
#define RSPLIT  25                  // row-groups per pixel-slice (32 rows each)

// Reconstruction
#define RPIX    64                  // pixels per recon block
#define RKS     8                   // k-slices (one per wave, 512 threads)
#define RKLEN   (NLR / RKS)         // 100 k per wave

// ---------------------------------------------------------------------------
// Kernel A: projection, atomic accumulation into coeffs[800][8].
// Lane: x[8 batch][4 pix] in regs, 8 basis-row float4 loads, 256 FMA, then a
// 6-level register reduce-scatter (63 shfl_xor) leaving lane l with the final
// partial for (r = l>>3, b = l&7). One coalesced 64-wide atomicAdd per wave.
// Basis read EXACTLY once chip-wide (82 MB); x ~20 MB L2; no LDS; no part[].
// ---------------------------------------------------------------------------
__global__ __launch_bounds__(256) void proj_kernel(
    const float* __restrict__ x,       // [8][25600]
    const float* __restrict__ basis,   // [800][25600]
    float* __restrict__ coeffs)        // [800][8], pre-zeroed
{
    const int tid   = threadIdx.x;
    const int lane  = tid & 63;
    const int wv    = tid >> 6;                       // 0..3
    const int p     = blockIdx.x;                     // pixel slice 0..99
    const int rbase = blockIdx.y * 32 + wv * 8;       // this wave's 8 rows
    const int px    = p * PPB + lane * 4;             // lane's first pixel

    // x in registers: 8 batch x float4 = 32 VGPR, loaded once
    float4 xv[BATCH];
    #pragma unroll
    for (int b = 0; b < BATCH; ++b)
        xv[b] = *(const float4*)(x + (size_t)b * PIX + px);

    // 8 basis rows, independent streams
    float4 bv[8];
    #pragma unroll
    for (int r = 0; r < 8; ++r)
        bv[r] = *(const float4*)(basis + (size_t)(rbase + r) * PIX + px);

    // v[i] = partial dot for (r = i>>3, b = i&7) over this lane's 4 pixels
    float v[64];
    #pragma unroll
    for (int r = 0; r < 8; ++r)
        #pragma unroll
        for (int b = 0; b < BATCH; ++b)
            v[r * 8 + b] = fmaf(bv[r].w, xv[b].w,
                           fmaf(bv[r].z, xv[b].z,
                           fmaf(bv[r].y, xv[b].y, bv[r].x * xv[b].x)));

    // Register reduce-scatter: 6 xor-levels; ends with lane l holding the
    // full 64-lane sum for index i == l. All register indices are static.
    #pragma unroll
    for (int k = 0; k < 6; ++k) {
        const int m  = 1 << k;
        const int kb = (lane >> k) & 1;
        const int n  = 64 >> k;
        #pragma unroll
        for (int j = 0; j < 32; ++j) {
            if (j < n / 2) {
                float a    = v[2 * j];
                float c    = v[2 * j + 1];
                float send = kb ? a : c;
                float keep = kb ? c : a;
                v[j] = keep + __shfl_xor(send, m);
            }
        }
    }

    // lane l owns (rbase + (l>>3), b = l&7) -> coeffs offset rbase*8 + l.
    // 64 consecutive addresses per wave: coalesced atomic.
    atomicAdd(&coeffs[(size_t)rbase * BATCH + lane], v[0]);
}

// ---------------------------------------------------------------------------
// Kernel B: rotation (fused into LDS staging) + reconstruction.
// grid = 400 blocks of 512 threads (8 waves). Staging rotates the 6400
// coefficients inline (13 sincos/thread); each wave owns a 100-k slice over
// 64 pixels; LDS tree-reduce across waves; direct coalesced stores.
// ---------------------------------------------------------------------------
__global__ __launch_bounds__(512) void recon_kernel(
    const float* __restrict__ basis,   // [800][25600]
    const float* __restrict__ coeffs,  // [800][8] (unrotated)
    const float* __restrict__ angles,  // [8]
    float* __restrict__ out)           // [8][25600]
{
    __shared__ float rl[NLR * BATCH];            // 25.6 KB rotated coeffs
    __shared__ float red[RKS - 1][BATCH][RPIX];  // 14.3 KB, lane-consecutive

    const int tid = threadIdx.x;

    // Stage + rotate: a = c0*ca + c1*sa ; b = c1*ca - c0*sa
    for (int idx = tid; idx < NLR * BATCH; idx += 512) {
        const int b   = idx & 7;
        const int nlr = idx >> 3;
        const int l   = (nlr >> 1) % LDIM;
        float self  = coeffs[idx];
        float other = coeffs[idx ^ 8];   // (nlr^1) partner
        float ca, sa;
        __sincosf(angles[b] * (float)l, &sa, &ca);
        rl[idx] = (nlr & 1) == 0 ? fmaf(self, ca, other * sa)
                                 : fmaf(self, ca, -other * sa);
    }
    __syncthreads();

    const int lane = tid & 63;
    const int ks   = tid >> 6;                 // wave = k-slice
    const int pix  = blockIdx.x * RPIX + lane;

    float acc[BATCH];
    #pragma unroll
    for (int b = 0; b < BATCH; ++b) acc[b] = 0.0f;

    const float* __restrict__ bp = basis + (size_t)(ks * RKLEN) * PIX + pix;
    const float* __restrict__ rp = &rl[(ks * RKLEN) * BATCH];

    #pragma unroll 10
    for (int k = 0; k < RKLEN; ++k) {
        float bvv = bp[(size_t)k * PIX];
        float4 v0 = *(const float4*)&rp[k * BATCH];
        float4 v1 = *(const float4*)&rp[k * BATCH + 4];
        acc[0] = fmaf(bvv, v0.x, acc[0]);
        acc[1] = fmaf(bvv, v0.y, acc[1]);
        acc[2] = fmaf(bvv, v0.z, acc[2]);
        acc[3] = fmaf(bvv, v0.w, acc[3]);
        acc[4] = fmaf(bvv, v1.x, acc[4]);
        acc[5] = fmaf(bvv, v1.y, acc[5]);
        acc[6] = fmaf(bvv, v1.z, acc[6]);
        acc[7] = fmaf(bvv, v1.w, acc[7]);
    }

    if (ks > 0) {
        #pragma unroll
        for (int b = 0; b < BATCH; ++b)
            red[ks - 1][b][lane] = acc[b];
    }
    __syncthreads();

    if (ks == 0) {
        #pragma unroll
        for (int w = 0; w < RKS - 1; ++w)
            #pragma unroll
            for (int b = 0; b < BATCH; ++b)
                acc[b] += red[w][b][lane];
        #pragma unroll
        for (int b = 0; b < BATCH; ++b)
            out[(size_t)b * PIX + pix] = acc[b];
    }
}

extern "C" void kernel_launch(void* const* d_in, const int* in_sizes, int n_in,
                              void* d_out, int out_size, void* d_ws, size_t ws_size,
                              hipStream_t stream) {
    (void)in_sizes; (void)n_in; (void)ws_size; (void)out_size;

    const float* x      = (const float*)d_in[0];   // [8][1][160][160]
    const float* basis  = (const float*)d_in[1];   // [20][20][2][160][160]
    const float* angles = (const float*)d_in[2];   // [8]
    float* out    = (float*)d_out;                 // [8][1][160][160]
    float* coeffs = (float*)d_ws;                  // [800][8] = 25.6 KB

    // Zero the atomic accumulation target (harness poisons d_ws).
    hipMemsetAsync(d_ws, 0, (size_t)NLR * BATCH * sizeof(float), stream);

    proj_kernel<<<dim3(NPX, RSPLIT), dim3(256), 0, stream>>>(x, basis, coeffs);
    recon_kernel<<<dim3(PIX / RPIX), dim3(512), 0, stream>>>(basis, coeffs, angles, out);
}